// Round 5
// baseline (196.797 us; speedup 1.0000x reference)
//
#include <hip/hip_runtime.h>

#define NUM_LABELS 512
#define CNT_BITS 25
#define CNT_MASK ((1LL << CNT_BITS) - 1)
#define FXSCALE 1048576.0f  // 2^20

// Pack one sample into a single u64 histogram update:
//   high 39 bits: fixed-point sum (value * 2^20), two's complement
//   low  25 bits: count (+1 per sample). Max count 2^25-1 = 33.5M > n.
__device__ __forceinline__ unsigned long long pack1(float v) {
  long long fx = (long long)__float2int_rn(v * FXSCALE);
  return ((unsigned long long)fx << CNT_BITS) + 1ULL;
}

__global__ __launch_bounds__(256) void accum_kernel(
    const int* __restrict__ labels,
    const float* __restrict__ vals,
    unsigned long long* __restrict__ g_hist,
    int n) {
  __shared__ unsigned long long s_hist[NUM_LABELS];
  for (int i = threadIdx.x; i < NUM_LABELS; i += 256) s_hist[i] = 0ULL;
  __syncthreads();

  const int n4 = n >> 2;
  const int tid = blockIdx.x * 256 + threadIdx.x;
  const int stride = gridDim.x * 256;
  const int4* l4 = reinterpret_cast<const int4*>(labels);
  const float4* v4 = reinterpret_cast<const float4*>(vals);

#define ACC4(L, V)                                   \
    atomicAdd(&s_hist[(L).x], pack1((V).x));         \
    atomicAdd(&s_hist[(L).y], pack1((V).y));         \
    atomicAdd(&s_hist[(L).z], pack1((V).z));         \
    atomicAdd(&s_hist[(L).w], pack1((V).w));

  int base = tid;
  // Fast path: 8 unconditional int4+float4 loads in flight (compile-time
  // register indices), then 32 LDS atomics. For n4 == 8*stride (the bench
  // shape) this runs exactly once per thread with no remainder.
  for (; base + 7 * stride < n4; base += 8 * stride) {
    int4 L[8];
    float4 V[8];
#pragma unroll
    for (int u = 0; u < 8; ++u) {
      L[u] = l4[base + u * stride];
      V[u] = v4[base + u * stride];
    }
#pragma unroll
    for (int u = 0; u < 8; ++u) {
      ACC4(L[u], V[u])
    }
  }
  // Remainder int4s
  for (; base < n4; base += stride) {
    int4 l = l4[base];
    float4 v = v4[base];
    ACC4(l, v)
  }
  // Scalar tail (n % 4)
  for (int t = (n4 << 2) + tid; t < n; t += stride) {
    atomicAdd(&s_hist[labels[t]], pack1(vals[t]));
  }
#undef ACC4
  __syncthreads();

  for (int j = threadIdx.x; j < NUM_LABELS; j += 256) {
    unsigned long long h = s_hist[j];
    if (h) atomicAdd(&g_hist[j], h);
  }
}

__global__ __launch_bounds__(256) void apply_kernel(
    const int* __restrict__ labels,
    const unsigned long long* __restrict__ g_hist,
    int* __restrict__ out,
    int n) {
  __shared__ int s_bad[NUM_LABELS];
  // Every block redundantly decodes the histogram -> bad flags (4 KB from L2).
  for (int j = threadIdx.x; j < NUM_LABELS; j += 256) {
    long long p = (long long)g_hist[j];
    int cnt = (int)(p & CNT_MASK);
    long long sf = p >> CNT_BITS;  // arithmetic shift: exact fixed-point sum
    int c = cnt > 1 ? cnt : 1;
    float mean = (float)((double)sf / ((double)FXSCALE * (double)c));
    s_bad[j] = ((mean < -0.003f) || (mean > 0.003f)) && (j != 0);
  }
  __syncthreads();

  const int n4 = n >> 2;
  const int tid = blockIdx.x * 256 + threadIdx.x;
  const int stride = gridDim.x * 256;
  const int4* l4 = reinterpret_cast<const int4*>(labels);
  int4* o4 = reinterpret_cast<int4*>(out);

#define FILT(L)                                      \
    { (L).x = s_bad[(L).x] ? 0 : (L).x;              \
      (L).y = s_bad[(L).y] ? 0 : (L).y;              \
      (L).z = s_bad[(L).z] ? 0 : (L).z;              \
      (L).w = s_bad[(L).w] ? 0 : (L).w; }

  int base = tid;
  for (; base + 7 * stride < n4; base += 8 * stride) {
    int4 L[8];
#pragma unroll
    for (int u = 0; u < 8; ++u) L[u] = l4[base + u * stride];
#pragma unroll
    for (int u = 0; u < 8; ++u) {
      FILT(L[u])
      o4[base + u * stride] = L[u];
    }
  }
  for (; base < n4; base += stride) {
    int4 l = l4[base];
    FILT(l)
    o4[base] = l;
  }
  for (int t = (n4 << 2) + tid; t < n; t += stride) {
    int l = labels[t];
    out[t] = s_bad[l] ? 0 : l;
  }
#undef FILT
}

extern "C" void kernel_launch(void* const* d_in, const int* in_sizes, int n_in,
                              void* d_out, int out_size, void* d_ws,
                              size_t ws_size, hipStream_t stream) {
  const int* labels = (const int*)d_in[0];
  const float* vals = (const float*)d_in[1];
  int* out = (int*)d_out;
  const int n = in_sizes[0];

  unsigned long long* g_hist = (unsigned long long*)d_ws;

  // ws is re-poisoned 0xAA before every timed launch — zero the histogram.
  hipMemsetAsync(d_ws, 0, NUM_LABELS * 8, stream);

  const int block = 256;
  const int grid = 2048;  // 8 blocks/CU on 256 CUs; n/4 == 8*grid*block here

  accum_kernel<<<grid, block, 0, stream>>>(labels, vals, g_hist, n);
  apply_kernel<<<grid, block, 0, stream>>>(labels, g_hist, out, n);
}